// Round 5
// baseline (168.673 us; speedup 1.0000x reference)
//
#include <hip/hip_runtime.h>
#include <hip/hip_bf16.h>

#define CIN 256
#define CRED 64
#define NB 4
#define NN 4096

typedef float v4f __attribute__((ext_vector_type(4)));
typedef short v8s __attribute__((ext_vector_type(8)));
typedef unsigned short u16;
typedef u16 u16x4 __attribute__((ext_vector_type(4)));
typedef u16 u16x8 __attribute__((ext_vector_type(8)));
typedef unsigned int u32;

#define LOG2E 1.4426950408889634f

__device__ __forceinline__ u16 f2bf(float f) {
    union { float f; u32 u; } v; v.f = f;
    u32 r = (v.u + 0x7FFFu + ((v.u >> 16) & 1u)) >> 16;  // RNE
    return (u16)r;
}
__device__ __forceinline__ float bf2f(u16 s) {
    union { u32 u; float f; } v; v.u = ((u32)s) << 16;
    return v.f;
}
// packed f32x2 -> bf16x2 (v_cvt_pk_bf16_f32 on gfx950), low half = a
__device__ __forceinline__ u32 pkbf(float a, float b) {
    float2 f; f.x = a; f.y = b;
    __hip_bfloat162 h = __float22bfloat162_rn(f);
    union { __hip_bfloat162 h; u32 u; } c; c.h = h;
    return c.u;
}
__device__ __forceinline__ v4f mfma16(v8s a, v8s b, v4f c) {
    return __builtin_amdgcn_mfma_f32_16x16x32_bf16(a, b, c, 0, 0, 0);
}
__device__ __forceinline__ float fexp2(float x) {
#if __has_builtin(__builtin_amdgcn_exp2f)
    return __builtin_amdgcn_exp2f(x);
#else
    return exp2f(x);
#endif
}

// ------------- kernel 0: weights -> bf16 ------------------------------------
__global__ __launch_bounds__(256) void k_wconv(const float* __restrict__ Wq,
                                               const float* __restrict__ Wk,
                                               const float* __restrict__ Wv,
                                               const float* __restrict__ Wp,
                                               u16* __restrict__ Wb,
                                               u16* __restrict__ WpB) {
    int t = threadIdx.x;
    if (blockIdx.x < 48) {
        int idx = (blockIdx.x * 256 + t) * 4;
        int row = idx >> 8;
        int mat = row >> 6, r = row & 63, col = idx & 255;
        const float* src = (mat == 0) ? Wq : (mat == 1) ? Wk : Wv;
        float4 v = *(const float4*)&src[r * 256 + col];
        float s = (mat == 0) ? (0.125f * LOG2E) : 1.0f;
        u16x4 o;
        o[0] = f2bf(v.x * s); o[1] = f2bf(v.y * s);
        o[2] = f2bf(v.z * s); o[3] = f2bf(v.w * s);
        *(u16x4*)&Wb[idx] = o;
    } else {
        int idx = ((blockIdx.x - 48) * 256 + t) * 4;
        float4 v = *(const float4*)&Wp[idx];
        u16x4 o;
        o[0] = f2bf(v.x); o[1] = f2bf(v.y);
        o[2] = f2bf(v.z); o[3] = f2bf(v.w);
        *(u16x4*)&WpB[idx] = o;
    }
}

// ------------- kernel 1: QKV projection via MFMA, 16 tokens/block -----------
// Q,K: (b,n,r) bf16 (Q scaled 0.125*log2e). V: (b,r,n) with key-permuted n
// inside each 64-tile: pos(n) = (n&15)*4 + ((n>>4)&3).
__global__ __launch_bounds__(256) void k_qkvm(const float* __restrict__ x,
                                              const u16* __restrict__ Wb,
                                              u16* __restrict__ Q, u16* __restrict__ K,
                                              u16* __restrict__ V) {
    int t = threadIdx.x;
    int wv = t >> 6, lane = t & 63, c15 = lane & 15, quad = lane >> 4;
    int b = blockIdx.x >> 8;
    int nb = (blockIdx.x & 255) * 16;
    const float* xb = x + ((size_t)b << 20);

    // A-frags straight from global: A[m=n_local][k=c]
    v8s Af[8];
    {
        const float* px = xb + nb + c15 + (size_t)quad * 8 * 4096;
#pragma unroll
        for (int kc = 0; kc < 8; ++kc) {
            float f[8];
#pragma unroll
            for (int j = 0; j < 8; ++j)
                f[j] = px[((size_t)kc * 32 + j) * 4096];
            union { v8s s; u32 w[4]; } pk;
            pk.w[0] = pkbf(f[0], f[1]); pk.w[1] = pkbf(f[2], f[3]);
            pk.w[2] = pkbf(f[4], f[5]); pk.w[3] = pkbf(f[6], f[7]);
            Af[kc] = pk.s;
        }
    }

    // wave wv -> output r-tiles 3wv..3wv+2 (0-3 Q, 4-7 K, 8-11 V)
#pragma unroll
    for (int rti = 0; rti < 3; ++rti) {
        int rt = wv * 3 + rti;
        const u16* wrow = Wb + (size_t)(rt * 16 + c15) * 256 + quad * 8;
        v4f acc = {0.f, 0.f, 0.f, 0.f};
#pragma unroll
        for (int kc = 0; kc < 8; ++kc) {
            v8s Bf = *(const v8s*)&wrow[kc * 32];
            acc = mfma16(Af[kc], Bf, acc);
        }
        // C layout: row(n_local) = quad*4+g, col(r_local) = c15
        if (rt < 8) {
            u16* base = (rt < 4) ? Q : K;
            u16* dst = base + ((size_t)b << 18)
                     + (size_t)(nb + quad * 4) * 64 + (rt & 3) * 16 + c15;
#pragma unroll
            for (int g = 0; g < 4; ++g) dst[g * 64] = f2bf(acc[g]);
        } else {
            // V permuted: n = nb+quad*4+g ; pos=(n&15)*4+((n>>4)&3)
            int hi2 = (nb >> 4) & 3;
            size_t base = ((size_t)b * 64 + (rt - 8) * 16 + c15) * 4096
                        + (size_t)(nb & ~63) + hi2;
#pragma unroll
            for (int g = 0; g < 4; ++g)
                V[base + (quad * 4 + g) * 4] = f2bf(acc[g]);
        }
    }
}

// ------------- kernel 2: flash attention, barrier-free ----------------------
// K/V B-frags read directly from global (L2-resident); no Kl/Vl, no barriers.
__global__ __launch_bounds__(256, 4) void k_flash(const u16* __restrict__ Q,
                                                  const u16* __restrict__ K,
                                                  const u16* __restrict__ V,
                                                  u16* __restrict__ OP,
                                                  float* __restrict__ Lb,
                                                  int sh) {
    __shared__ u16 Pl[4][32][72];    // per-wave P: [row][pos], pos=(key&15)*4+(key>>4)
    int t = threadIdx.x;
    int p = blockIdx.x & ((1u << sh) - 1);
    int tile = blockIdx.x >> sh;
    int b = tile >> 5;
    int n0 = (tile & 31) * 128;
    int wv = t >> 6;
    int lane = t & 63;
    int c15 = lane & 15;
    int quad = lane >> 4;
    int nw = n0 + wv * 32;
    const u16* Qb = Q + (size_t)b * NN * 64;
    int mlen = NN >> sh;
    int m0 = p * mlen;
    int iters = mlen >> 6;

    // lane-resolved streaming pointers
    const u16* kp = K + (size_t)b * NN * 64 + (size_t)(m0 + c15) * 64 + quad * 8;
    const u16* vp = V + (size_t)b * 64 * NN + (size_t)c15 * NN + m0 + quad * 8;

    v8s Qa[2][2];
#pragma unroll
    for (int rg = 0; rg < 2; ++rg)
#pragma unroll
        for (int c2 = 0; c2 < 2; ++c2)
            Qa[rg][c2] = *(const v8s*)&Qb[(size_t)(nw + rg * 16 + c15) * 64 + c2 * 32 + quad * 8];

    v4f O[2][4];
    float ls[2][4];
#pragma unroll
    for (int rg = 0; rg < 2; ++rg)
#pragma unroll
        for (int g = 0; g < 4; ++g) {
            ls[rg][g] = 0.f;
#pragma unroll
            for (int cg = 0; cg < 4; ++cg) O[rg][cg][g] = 0.f;
        }

    for (int it = 0; it < iters; ++it) {
        size_t ko = (size_t)it * 64 * 64;   // key rows advance in (n,r) layout
        size_t vo = (size_t)it * 64;        // pos columns advance in (r,pos) layout

        v4f S[2][4];
#pragma unroll
        for (int rg = 0; rg < 2; ++rg)
#pragma unroll
            for (int s = 0; s < 4; ++s)
#pragma unroll
                for (int g = 0; g < 4; ++g) S[rg][s][g] = 0.f;
#pragma unroll
        for (int s = 0; s < 4; ++s) {
            v8s kb0 = *(const v8s*)&kp[ko + (size_t)s * 16 * 64];
            v8s kb1 = *(const v8s*)&kp[ko + (size_t)s * 16 * 64 + 32];
            S[0][s] = mfma16(Qa[0][0], kb0, S[0][s]);
            S[1][s] = mfma16(Qa[1][0], kb0, S[1][s]);
            S[0][s] = mfma16(Qa[0][1], kb1, S[0][s]);
            S[1][s] = mfma16(Qa[1][1], kb1, S[1][s]);
        }

        // fixed-max softmax: P = 2^s ; packed writes to permuted columns
#pragma unroll
        for (int rg = 0; rg < 2; ++rg) {
            float E[4][4];
#pragma unroll
            for (int s = 0; s < 4; ++s)
#pragma unroll
                for (int g = 0; g < 4; ++g) {
                    float e = fexp2(S[rg][s][g]);
                    E[s][g] = e;
                    ls[rg][g] += e;
                }
#pragma unroll
            for (int g = 0; g < 4; ++g) {
                union { u16x4 v; u32 w[2]; } p2;
                p2.w[0] = pkbf(E[0][g], E[1][g]);
                p2.w[1] = pkbf(E[2][g], E[3][g]);
                *(u16x4*)&Pl[wv][rg * 16 + quad * 4 + g][c15 * 4] = p2.v;
            }
        }
        // per-wave LDS round-trip: lgkmcnt orders intra-wave, no barrier

        v8s Pa[2][2];
#pragma unroll
        for (int rg = 0; rg < 2; ++rg)
#pragma unroll
            for (int c2 = 0; c2 < 2; ++c2)
                Pa[rg][c2] = *(const v8s*)&Pl[wv][rg * 16 + c15][c2 * 32 + quad * 8];
#pragma unroll
        for (int cg = 0; cg < 4; ++cg) {
            v8s vb0 = *(const v8s*)&vp[(size_t)cg * 16 * NN + vo];
            v8s vb1 = *(const v8s*)&vp[(size_t)cg * 16 * NN + vo + 32];
            O[0][cg] = mfma16(Pa[0][0], vb0, O[0][cg]);
            O[1][cg] = mfma16(Pa[1][0], vb0, O[1][cg]);
            O[0][cg] = mfma16(Pa[0][1], vb1, O[0][cg]);
            O[1][cg] = mfma16(Pa[1][1], vb1, O[1][cg]);
        }
    }

    u16* OPp = OP + (size_t)p * (NB * NN * 64) + (size_t)b * NN * 64;
#pragma unroll
    for (int rg = 0; rg < 2; ++rg)
#pragma unroll
        for (int cg = 0; cg < 4; ++cg)
#pragma unroll
            for (int g = 0; g < 4; ++g) {
                int n = nw + rg * 16 + quad * 4 + g;
                OPp[(size_t)n * 64 + cg * 16 + c15] = f2bf(O[rg][cg][g]);
            }
#pragma unroll
    for (int rg = 0; rg < 2; ++rg)
#pragma unroll
        for (int g = 0; g < 4; ++g) {
            float v = ls[rg][g];
#pragma unroll
            for (int off = 1; off <= 8; off <<= 1) v += __shfl_xor(v, off);
            ls[rg][g] = v;
        }
    if (c15 == 0) {
        float* Lp = Lb + (size_t)p * (NB * NN) + (size_t)b * NN;
#pragma unroll
        for (int rg = 0; rg < 2; ++rg)
#pragma unroll
            for (int g = 0; g < 4; ++g) {
                int n = nw + rg * 16 + quad * 4 + g;
                Lp[n] = ls[rg][g];
            }
    }
}

// ------------- kernel 3: merge splits + Wp MFMA projection + residual -------
#define OMP 72
__global__ __launch_bounds__(256) void k_proj(const u16* __restrict__ OP,
                                              const float* __restrict__ Lb,
                                              const u16* __restrict__ WpB,
                                              const float* __restrict__ x,
                                              float* __restrict__ out,
                                              int nsp) {
    __shared__ u16 Om[16 * OMP];    // merged normalized O: [n][r]
    int t = threadIdx.x;
    int b = blockIdx.x >> 8;
    int n0 = (blockIdx.x & 255) * 16;

    {
        int n_l = t >> 4, r0 = (t & 15) * 4;
        size_t nidx = (size_t)b * NN + n0 + n_l;
        float o[4] = {0.f, 0.f, 0.f, 0.f};
        float l = 0.f;
        for (int p = 0; p < nsp; ++p) {
            u16x4 u = *(const u16x4*)&OP[((size_t)p * (NB * NN) + nidx) * 64 + r0];
#pragma unroll
            for (int j = 0; j < 4; ++j) o[j] += bf2f(u[j]);
            l += Lb[(size_t)p * (NB * NN) + nidx];
        }
        float inv = 1.0f / l;
        union { u16x4 v; u32 w[2]; } p2;
        p2.w[0] = pkbf(o[0] * inv, o[1] * inv);
        p2.w[1] = pkbf(o[2] * inv, o[3] * inv);
        *(u16x4*)&Om[n_l * OMP + r0] = p2.v;
    }
    __syncthreads();

    int lane = t & 63, wvv = t >> 6, c15 = lane & 15, quad = lane >> 4;
    v8s B0 = *(const v8s*)&Om[c15 * OMP + quad * 8];
    v8s B1 = *(const v8s*)&Om[c15 * OMP + 32 + quad * 8];
#pragma unroll
    for (int ct0 = 0; ct0 < 4; ++ct0) {
        int ct = wvv * 4 + ct0;
        const u16* wrow = WpB + (size_t)(ct * 16 + c15) * 64 + quad * 8;
        v8s A0 = *(const v8s*)&wrow[0];
        v8s A1 = *(const v8s*)&wrow[32];
        v4f acc = {0.f, 0.f, 0.f, 0.f};
        acc = mfma16(A0, B0, acc);
        acc = mfma16(A1, B1, acc);
        size_t base = ((size_t)(b * 256 + ct * 16 + quad * 4)) * 4096 + n0 + c15;
#pragma unroll
        for (int g = 0; g < 4; ++g)
            out[base + (size_t)g * 4096] = acc[g] + x[base + (size_t)g * 4096];
    }
}

extern "C" void kernel_launch(void* const* d_in, const int* in_sizes, int n_in,
                              void* d_out, int out_size, void* d_ws, size_t ws_size,
                              hipStream_t stream) {
    const float* x  = (const float*)d_in[0];
    const float* Wq = (const float*)d_in[1];
    const float* Wk = (const float*)d_in[2];
    const float* Wv = (const float*)d_in[3];
    const float* Wp = (const float*)d_in[4];
    float* out = (float*)d_out;
    char* ws = (char*)d_ws;

    int nsp = (ws_size >= (size_t)24 * 1024 * 1024) ? 8 : 4;
    int sh = (nsp == 8) ? 3 : 2;

    u16* Wb  = (u16*)(ws);                                   // 96 KB
    u16* WpB = (u16*)(ws + 131072);                          // 32 KB
    u16* Q   = (u16*)(ws + 262144);                          // 2 MB
    u16* K   = (u16*)(ws + 262144 + 2097152);                // 2 MB
    u16* V   = (u16*)(ws + 262144 + 2 * 2097152);            // 2 MB
    u16* OP  = (u16*)(ws + 262144 + 3 * 2097152);            // nsp*2 MB
    float* Lbuf = (float*)(ws + 262144 + (size_t)(3 + nsp) * 2097152);

    k_wconv<<<64, 256, 0, stream>>>(Wq, Wk, Wv, Wp, Wb, WpB);
    k_qkvm<<<NB * 256, 256, 0, stream>>>(x, Wb, Q, K, V);
    k_flash<<<NB * 32 * nsp, 256, 0, stream>>>(Q, K, V, OP, Lbuf, sh);
    k_proj<<<NB * 256, 256, 0, stream>>>(OP, Lbuf, WpB, x, out, nsp);
}

// Round 6
// 126.076 us; speedup vs baseline: 1.3379x; 1.3379x over previous
//
#include <hip/hip_runtime.h>
#include <hip/hip_bf16.h>

#define CIN 256
#define CRED 64
#define NB 4
#define NN 4096

typedef float v4f __attribute__((ext_vector_type(4)));
typedef short v8s __attribute__((ext_vector_type(8)));
typedef unsigned short u16;
typedef u16 u16x4 __attribute__((ext_vector_type(4)));
typedef u16 u16x8 __attribute__((ext_vector_type(8)));
typedef unsigned int u32;

#define LOG2E 1.4426950408889634f

__device__ __forceinline__ u16 f2bf(float f) {
    union { float f; u32 u; } v; v.f = f;
    u32 r = (v.u + 0x7FFFu + ((v.u >> 16) & 1u)) >> 16;  // RNE
    return (u16)r;
}
__device__ __forceinline__ float bf2f(u16 s) {
    union { u32 u; float f; } v; v.u = ((u32)s) << 16;
    return v.f;
}
// packed f32x2 -> bf16x2 (v_cvt_pk_bf16_f32 on gfx950), low half = a
__device__ __forceinline__ u32 pkbf(float a, float b) {
    float2 f; f.x = a; f.y = b;
    __hip_bfloat162 h = __float22bfloat162_rn(f);
    union { __hip_bfloat162 h; u32 u; } c; c.h = h;
    return c.u;
}
__device__ __forceinline__ v4f mfma16(v8s a, v8s b, v4f c) {
    return __builtin_amdgcn_mfma_f32_16x16x32_bf16(a, b, c, 0, 0, 0);
}
__device__ __forceinline__ float fexp2(float x) {
#if __has_builtin(__builtin_amdgcn_exp2f)
    return __builtin_amdgcn_exp2f(x);
#else
    return exp2f(x);
#endif
}

// ------------- kernel 0: weights -> bf16 ------------------------------------
__global__ __launch_bounds__(256) void k_wconv(const float* __restrict__ Wq,
                                               const float* __restrict__ Wk,
                                               const float* __restrict__ Wv,
                                               const float* __restrict__ Wp,
                                               u16* __restrict__ Wb,
                                               u16* __restrict__ WpB) {
    int t = threadIdx.x;
    if (blockIdx.x < 48) {
        int idx = (blockIdx.x * 256 + t) * 4;
        int row = idx >> 8;
        int mat = row >> 6, r = row & 63, col = idx & 255;
        const float* src = (mat == 0) ? Wq : (mat == 1) ? Wk : Wv;
        float4 v = *(const float4*)&src[r * 256 + col];
        float s = (mat == 0) ? (0.125f * LOG2E) : 1.0f;
        u16x4 o;
        o[0] = f2bf(v.x * s); o[1] = f2bf(v.y * s);
        o[2] = f2bf(v.z * s); o[3] = f2bf(v.w * s);
        *(u16x4*)&Wb[idx] = o;
    } else {
        int idx = ((blockIdx.x - 48) * 256 + t) * 4;
        float4 v = *(const float4*)&Wp[idx];
        u16x4 o;
        o[0] = f2bf(v.x); o[1] = f2bf(v.y);
        o[2] = f2bf(v.z); o[3] = f2bf(v.w);
        *(u16x4*)&WpB[idx] = o;
    }
}

// ------------- kernel 1: QKV projection via MFMA, 32 tokens/block (R4) ------
// Q,K: (b,n,r) bf16 (Q scaled 0.125*log2e). V: (b,r,n) with key-permuted n
// inside each 64-tile: pos(n) = (n&15)*4 + ((n>>4)&3).
__global__ __launch_bounds__(256) void k_qkvm(const float* __restrict__ x,
                                              const u16* __restrict__ Wb,
                                              u16* __restrict__ Q, u16* __restrict__ K,
                                              u16* __restrict__ V) {
    int t = threadIdx.x;
    int wv = t >> 6, lane = t & 63, c15 = lane & 15, quad = lane >> 4;
    int n0g = blockIdx.x * 32;
    int b = n0g >> 12, nb = n0g & 4095;
    const float* xb = x + ((size_t)b << 20);

    // A-frags straight from global: A[m=n_local][k=c]
    v8s Af[2][8];
#pragma unroll
    for (int nt = 0; nt < 2; ++nt) {
        const float* px = xb + nb + nt * 16 + c15 + (size_t)quad * 8 * 4096;
#pragma unroll
        for (int kc = 0; kc < 8; ++kc) {
            float f[8];
#pragma unroll
            for (int j = 0; j < 8; ++j)
                f[j] = px[((size_t)kc * 32 + j) * 4096];
            union { v8s s; u32 w[4]; } pk;
            pk.w[0] = pkbf(f[0], f[1]); pk.w[1] = pkbf(f[2], f[3]);
            pk.w[2] = pkbf(f[4], f[5]); pk.w[3] = pkbf(f[6], f[7]);
            Af[nt][kc] = pk.s;
        }
    }

    // wave wv -> output r-tiles 3wv..3wv+2 (0-3 Q, 4-7 K, 8-11 V)
#pragma unroll
    for (int rti = 0; rti < 3; ++rti) {
        int rt = wv * 3 + rti;
        const u16* wrow = Wb + (size_t)(rt * 16 + c15) * 256 + quad * 8;
        v8s Bf[8];
#pragma unroll
        for (int kc = 0; kc < 8; ++kc) Bf[kc] = *(const v8s*)&wrow[kc * 32];
#pragma unroll
        for (int nt = 0; nt < 2; ++nt) {
            v4f acc = {0.f, 0.f, 0.f, 0.f};
#pragma unroll
            for (int kc = 0; kc < 8; ++kc)
                acc = mfma16(Af[nt][kc], Bf[kc], acc);
            // C layout: row(n_local) = quad*4+g, col(r_local) = c15
            if (rt < 8) {
                u16* base = (rt < 4) ? Q : K;
                u16* dst = base + ((size_t)b << 18)
                         + (size_t)(nb + nt * 16 + quad * 4) * 64
                         + (rt & 3) * 16 + c15;
#pragma unroll
                for (int g = 0; g < 4; ++g) dst[g * 64] = f2bf(acc[g]);
            } else {
                // V permuted: n = nb+nt*16+quad*4+g ; pos=(n&15)*4+((n>>4)&3)
                int hi2 = ((nb + nt * 16) >> 4) & 3;
                size_t base = ((size_t)b * 64 + (rt - 8) * 16 + c15) * 4096
                            + (size_t)((nb + nt * 16) & ~63) + hi2;
#pragma unroll
                for (int g = 0; g < 4; ++g)
                    V[base + (quad * 4 + g) * 4] = f2bf(acc[g]);
            }
        }
    }
}

// ------------- kernel 2: flash attention, LDS-staged + register prefetch ----
__global__ __launch_bounds__(256, 4) void k_flash(const u16* __restrict__ Q,
                                                  const u16* __restrict__ K,
                                                  const u16* __restrict__ V,
                                                  u16* __restrict__ OP,
                                                  float* __restrict__ Lb,
                                                  int sh) {
    __shared__ u16 Kl[64][72];       // K tile (m,r)
    __shared__ u16 Vl[64][72];       // V tile (r, pos)
    __shared__ u16 Pl[4][32][72];    // per-wave P: [row][pos], pos=(key&15)*4+(key>>4)
    int t = threadIdx.x;
    int p = blockIdx.x & ((1u << sh) - 1);
    int tile = blockIdx.x >> sh;
    int b = tile >> 5;
    int n0 = (tile & 31) * 128;
    int wv = t >> 6;
    int lane = t & 63;
    int c15 = lane & 15;
    int quad = lane >> 4;
    int nw = n0 + wv * 32;
    const u16* Qb = Q + (size_t)b * NN * 64;
    const u16* Kb = K + (size_t)b * NN * 64;
    const u16* Vb = V + (size_t)b * 64 * NN;

    v8s Qa[2][2];
#pragma unroll
    for (int rg = 0; rg < 2; ++rg)
#pragma unroll
        for (int c2 = 0; c2 < 2; ++c2)
            Qa[rg][c2] = *(const v8s*)&Qb[(size_t)(nw + rg * 16 + c15) * 64 + c2 * 32 + quad * 8];

    v4f O[2][4];
    float ls[2][4];
#pragma unroll
    for (int rg = 0; rg < 2; ++rg)
#pragma unroll
        for (int g = 0; g < 4; ++g) {
            ls[rg][g] = 0.f;
#pragma unroll
            for (int cg = 0; cg < 4; ++cg) O[rg][cg][g] = 0.f;
        }

    int mlen = NN >> sh;
    int m0 = p * mlen;
    int iters = mlen >> 6;
    int srow = t >> 3, scol = (t & 7) * 8;

    // prefetch tile 0 into registers
    v8s kpre[2], vpre[2];
#pragma unroll
    for (int pass = 0; pass < 2; ++pass) {
        int rr = srow + pass * 32;
        kpre[pass] = *(const v8s*)&Kb[(size_t)(m0 + rr) * 64 + scol];
        vpre[pass] = *(const v8s*)&Vb[(size_t)rr * NN + m0 + scol];
    }

    for (int it = 0; it < iters; ++it) {
        // commit prefetched tile to LDS
#pragma unroll
        for (int pass = 0; pass < 2; ++pass) {
            int rr = srow + pass * 32;
            *(v8s*)&Kl[rr][scol] = kpre[pass];
            *(v8s*)&Vl[rr][scol] = vpre[pass];
        }
        __syncthreads();

        // issue next tile's global loads now; vmcnt waits land next iteration
        if (it + 1 < iters) {
            int mt = m0 + (it + 1) * 64;
#pragma unroll
            for (int pass = 0; pass < 2; ++pass) {
                int rr = srow + pass * 32;
                kpre[pass] = *(const v8s*)&Kb[(size_t)(mt + rr) * 64 + scol];
                vpre[pass] = *(const v8s*)&Vb[(size_t)rr * NN + mt + scol];
            }
        }

        v4f S[2][4];
#pragma unroll
        for (int rg = 0; rg < 2; ++rg)
#pragma unroll
            for (int s = 0; s < 4; ++s)
#pragma unroll
                for (int g = 0; g < 4; ++g) S[rg][s][g] = 0.f;
#pragma unroll
        for (int s = 0; s < 4; ++s)
#pragma unroll
            for (int c2 = 0; c2 < 2; ++c2) {
                v8s kb = *(const v8s*)&Kl[s * 16 + c15][c2 * 32 + quad * 8];
                S[0][s] = mfma16(Qa[0][c2], kb, S[0][s]);
                S[1][s] = mfma16(Qa[1][c2], kb, S[1][s]);
            }

        // fixed-max softmax: P = 2^s ; packed writes to permuted columns
#pragma unroll
        for (int rg = 0; rg < 2; ++rg) {
            float E[4][4];
#pragma unroll
            for (int s = 0; s < 4; ++s)
#pragma unroll
                for (int g = 0; g < 4; ++g) {
                    float e = fexp2(S[rg][s][g]);
                    E[s][g] = e;
                    ls[rg][g] += e;
                }
#pragma unroll
            for (int g = 0; g < 4; ++g) {
                union { u16x4 v; u32 w[2]; } p2;
                p2.w[0] = pkbf(E[0][g], E[1][g]);
                p2.w[1] = pkbf(E[2][g], E[3][g]);
                *(u16x4*)&Pl[wv][rg * 16 + quad * 4 + g][c15 * 4] = p2.v;
            }
        }
        // per-wave LDS round-trip: lgkmcnt orders intra-wave, no barrier

        v8s Pa[2][2];
#pragma unroll
        for (int rg = 0; rg < 2; ++rg)
#pragma unroll
            for (int c2 = 0; c2 < 2; ++c2)
                Pa[rg][c2] = *(const v8s*)&Pl[wv][rg * 16 + c15][c2 * 32 + quad * 8];
#pragma unroll
        for (int cg = 0; cg < 4; ++cg)
#pragma unroll
            for (int c2 = 0; c2 < 2; ++c2) {
                v8s vb = *(const v8s*)&Vl[cg * 16 + c15][c2 * 32 + quad * 8];
                O[0][cg] = mfma16(Pa[0][c2], vb, O[0][cg]);
                O[1][cg] = mfma16(Pa[1][c2], vb, O[1][cg]);
            }
        __syncthreads();   // all waves done with Kl/Vl before next commit
    }

    u16* OPp = OP + (size_t)p * (NB * NN * 64) + (size_t)b * NN * 64;
#pragma unroll
    for (int rg = 0; rg < 2; ++rg)
#pragma unroll
        for (int cg = 0; cg < 4; ++cg)
#pragma unroll
            for (int g = 0; g < 4; ++g) {
                int n = nw + rg * 16 + quad * 4 + g;
                OPp[(size_t)n * 64 + cg * 16 + c15] = f2bf(O[rg][cg][g]);
            }
#pragma unroll
    for (int rg = 0; rg < 2; ++rg)
#pragma unroll
        for (int g = 0; g < 4; ++g) {
            float v = ls[rg][g];
#pragma unroll
            for (int off = 1; off <= 8; off <<= 1) v += __shfl_xor(v, off);
            ls[rg][g] = v;
        }
    if (c15 == 0) {
        float* Lp = Lb + (size_t)p * (NB * NN) + (size_t)b * NN;
#pragma unroll
        for (int rg = 0; rg < 2; ++rg)
#pragma unroll
            for (int g = 0; g < 4; ++g) {
                int n = nw + rg * 16 + quad * 4 + g;
                Lp[n] = ls[rg][g];
            }
    }
}

// ------------- kernel 3: merge splits + Wp MFMA projection + residual -------
#define OMP 72
__global__ __launch_bounds__(256) void k_proj(const u16* __restrict__ OP,
                                              const float* __restrict__ Lb,
                                              const u16* __restrict__ WpB,
                                              const float* __restrict__ x,
                                              float* __restrict__ out,
                                              int nsp) {
    __shared__ u16 Om[16 * OMP];    // merged normalized O: [n][r]
    int t = threadIdx.x;
    int b = blockIdx.x >> 8;
    int n0 = (blockIdx.x & 255) * 16;

    {
        int n_l = t >> 4, r0 = (t & 15) * 4;
        size_t nidx = (size_t)b * NN + n0 + n_l;
        float o[4] = {0.f, 0.f, 0.f, 0.f};
        float l = 0.f;
        for (int p = 0; p < nsp; ++p) {
            u16x4 u = *(const u16x4*)&OP[((size_t)p * (NB * NN) + nidx) * 64 + r0];
#pragma unroll
            for (int j = 0; j < 4; ++j) o[j] += bf2f(u[j]);
            l += Lb[(size_t)p * (NB * NN) + nidx];
        }
        float inv = 1.0f / l;
        union { u16x4 v; u32 w[2]; } p2;
        p2.w[0] = pkbf(o[0] * inv, o[1] * inv);
        p2.w[1] = pkbf(o[2] * inv, o[3] * inv);
        *(u16x4*)&Om[n_l * OMP + r0] = p2.v;
    }
    __syncthreads();

    int lane = t & 63, wvv = t >> 6, c15 = lane & 15, quad = lane >> 4;
    v8s B0 = *(const v8s*)&Om[c15 * OMP + quad * 8];
    v8s B1 = *(const v8s*)&Om[c15 * OMP + 32 + quad * 8];
#pragma unroll
    for (int ct0 = 0; ct0 < 4; ++ct0) {
        int ct = wvv * 4 + ct0;
        const u16* wrow = WpB + (size_t)(ct * 16 + c15) * 64 + quad * 8;
        v8s A0 = *(const v8s*)&wrow[0];
        v8s A1 = *(const v8s*)&wrow[32];
        v4f acc = {0.f, 0.f, 0.f, 0.f};
        acc = mfma16(A0, B0, acc);
        acc = mfma16(A1, B1, acc);
        size_t base = ((size_t)(b * 256 + ct * 16 + quad * 4)) * 4096 + n0 + c15;
#pragma unroll
        for (int g = 0; g < 4; ++g)
            out[base + (size_t)g * 4096] = acc[g] + x[base + (size_t)g * 4096];
    }
}

extern "C" void kernel_launch(void* const* d_in, const int* in_sizes, int n_in,
                              void* d_out, int out_size, void* d_ws, size_t ws_size,
                              hipStream_t stream) {
    const float* x  = (const float*)d_in[0];
    const float* Wq = (const float*)d_in[1];
    const float* Wk = (const float*)d_in[2];
    const float* Wv = (const float*)d_in[3];
    const float* Wp = (const float*)d_in[4];
    float* out = (float*)d_out;
    char* ws = (char*)d_ws;

    int nsp = (ws_size >= (size_t)24 * 1024 * 1024) ? 8 : 4;
    int sh = (nsp == 8) ? 3 : 2;

    u16* Wb  = (u16*)(ws);                                   // 96 KB
    u16* WpB = (u16*)(ws + 131072);                          // 32 KB
    u16* Q   = (u16*)(ws + 262144);                          // 2 MB
    u16* K   = (u16*)(ws + 262144 + 2097152);                // 2 MB
    u16* V   = (u16*)(ws + 262144 + 2 * 2097152);            // 2 MB
    u16* OP  = (u16*)(ws + 262144 + 3 * 2097152);            // nsp*2 MB
    float* Lbuf = (float*)(ws + 262144 + (size_t)(3 + nsp) * 2097152);

    k_wconv<<<64, 256, 0, stream>>>(Wq, Wk, Wv, Wp, Wb, WpB);
    k_qkvm<<<512, 256, 0, stream>>>(x, Wb, Q, K, V);
    k_flash<<<NB * 32 * nsp, 256, 0, stream>>>(Q, K, V, OP, Lbuf, sh);
    k_proj<<<NB * 256, 256, 0, stream>>>(OP, Lbuf, WpB, x, out, nsp);
}